// Round 6
// baseline (3446.820 us; speedup 1.0000x reference)
//
#include <hip/hip_runtime.h>
#include <math.h>

#define K_NN 11
#define B_   1024
#define D_   64
#define A_   4
#define C_   50000
#define NCH  4
#define CPC  12500               // candidates per chunk
#define NTT  49                  // 256-wide c-tiles per chunk (48 full + 212 tail)
#define TW   256                 // tile width (candidates)

// ---------------- K0: s2[a,c] = sum(ts[a,c,:]^2) ----------------
__global__ __launch_bounds__(256) void s2_kernel(const float* __restrict__ ts,
                                                 float* __restrict__ s2g) {
  const int gwid = (blockIdx.x * 256 + threadIdx.x) >> 6;
  const int lane = threadIdx.x & 63;
  const int r0 = gwid * 16;
  if (r0 >= A_ * C_) return;
  const float4* t4 = (const float4*)ts;
  #pragma unroll
  for (int i = 0; i < 4; ++i) {
    const int fi = i * 64 + lane;
    const int r  = r0 + (fi >> 4);
    const int k  = fi & 15;
    float4 v = t4[(size_t)r * 16 + k];
    float acc = v.x*v.x + v.y*v.y + v.z*v.z + v.w*v.w;
    #pragma unroll
    for (int off = 1; off < 16; off <<= 1) acc += __shfl_xor(acc, off, 64);
    if ((lane & 15) == 0) s2g[r] = acc;
  }
}

// ---------------- K1: d-major tile, m=4 rows/wave, n=4 cands/lane ----------
// grid 1024 = 64 rowgroups x 4 a x 4 ch; block 256 thr = 4 waves.
// Wave owns 4 rows (o[r] distributed: o[r]=obs[row][lane]); lane owns cands
// 4*lane..4*lane+3 of each 256-wide tile. LDS: single 32KB d-major tile
// sb[32 d][256 c], reg-staged prefetch (T14). Lists: lane r owns row r.

__global__ __launch_bounds__(256) void qec_kernel(
    const float* __restrict__ obs, const float* __restrict__ ts,
    const float* __restrict__ s2g, float* __restrict__ pscore,
    int* __restrict__ pidx)
{
  __shared__ float sb[32 * 256];            // 32 KB single buffer

  const int tid  = threadIdx.x;
  const int lane = tid & 63;
  const int w    = tid >> 6;
  const int x    = blockIdx.x & 15;         // (a,ch) spread across XCDs
  const int a    = x >> 2;
  const int ch   = x & 3;
  const int rg   = blockIdx.x >> 4;         // 0..63
  const int b0w  = rg * 16 + w * 4;         // this wave's 4 rows

  const float* tsa = ts  + (size_t)a * C_ * 64;
  const float* s2a = s2g + (size_t)a * C_;
  const int cbase = ch * CPC;
  const int cend  = cbase + CPC;

  // distributed obs: o[r] = obs[b0w+r][lane]   (4 VGPRs)
  float o[4];
  #pragma unroll
  for (int r = 0; r < 4; ++r) o[r] = obs[(size_t)(b0w + r) * 64 + lane];

  float best[K_NN]; int bix[K_NN];
  float tau[4]; int tix[4];
  #pragma unroll
  for (int j = 0; j < K_NN; ++j) { best[j] = INFINITY; bix[j] = 0x7fffffff; }
  #pragma unroll
  for (int r = 0; r < 4; ++r) { tau[r] = INFINITY; tix[r] = 0x7fffffff; }

  float acc[4][4];                          // [row][ci]
  float4 stg[8];                            // staged regs (32 VGPR)
  const int ct = tid;                       // candidate column owned for staging

  // LOADS(t,h): thread reads its column's 8 float4s for d-half h
#define LOADS(T, H)                                                         \
  {                                                                         \
    const int c = min(cbase + (T) * TW + ct, C_ - 1);                       \
    const float* src = tsa + (size_t)c * 64 + (H) * 32;                     \
    _Pragma("unroll")                                                       \
    for (int q = 0; q < 8; ++q) stg[q] = *(const float4*)(src + 4 * q);     \
  }
  // WRITES: d-major scatter, per-instr banks = (4*ct)%128B -> 2-way free
#define WRITES()                                                            \
  {                                                                         \
    _Pragma("unroll")                                                       \
    for (int q = 0; q < 8; ++q) {                                           \
      sb[(4*q+0) * 256 + ct] = stg[q].x;                                    \
      sb[(4*q+1) * 256 + ct] = stg[q].y;                                    \
      sb[(4*q+2) * 256 + ct] = stg[q].z;                                    \
      sb[(4*q+3) * 256 + ct] = stg[q].w;                                    \
    }                                                                       \
  }
#define COMPUTE(H)                                                          \
  {                                                                         \
    _Pragma("unroll")                                                       \
    for (int dl = 0; dl < 32; ++dl) {                                       \
      const float4 cv = *(const float4*)&sb[dl * 256 + 4 * lane];           \
      const int da = ((H) << 5) + dl;                                       \
      _Pragma("unroll")                                                     \
      for (int r = 0; r < 4; ++r) {                                         \
        const float ov = __uint_as_float(                                   \
            __builtin_amdgcn_readlane(__float_as_uint(o[r]), da));          \
        acc[r][0] = fmaf(cv.x, ov, acc[r][0]);                              \
        acc[r][1] = fmaf(cv.y, ov, acc[r][1]);                              \
        acc[r][2] = fmaf(cv.z, ov, acc[r][2]);                              \
        acc[r][3] = fmaf(cv.w, ov, acc[r][3]);                              \
      }                                                                     \
    }                                                                       \
  }

  // prologue: stage tile 0 half 0
  LOADS(0, 0);
  WRITES();
  __syncthreads();

  float4 sq4 = make_float4(0.f, 0.f, 0.f, 0.f);

  for (int t = 0; t < NTT; ++t) {
    const int c0 = cbase + t * TW;

    // ---- half 0 ----
    LOADS(t, 1);                            // prefetch half 1
    #pragma unroll
    for (int r = 0; r < 4; ++r)
      #pragma unroll
      for (int ci = 0; ci < 4; ++ci) acc[r][ci] = 0.f;
    sq4 = *(const float4*)(s2a + min(c0 + 4 * lane, C_ - 4));
    COMPUTE(0);
    __syncthreads();
    WRITES();
    __syncthreads();

    // ---- half 1 ----
    if (t + 1 < NTT) LOADS(t + 1, 0);       // prefetch next tile half 0
    COMPUTE(1);

    // ---- selection (lex-exact, shared-tau, owner-lane lists) ----
    {
      const float sqv[4] = {sq4.x, sq4.y, sq4.z, sq4.w};
      #pragma unroll
      for (int ci = 0; ci < 4; ++ci) {
        const int cid = c0 + 4 * lane + ci;
        #pragma unroll
        for (int r = 0; r < 4; ++r) {
          const float sc = fmaf(-2.f, acc[r][ci], sqv[ci]);
          const bool pass = (cid < cend) &&
              ((sc < tau[r]) || (sc == tau[r] && cid < tix[r]));
          unsigned long long m = __ballot(pass);
          while (m) {
            const int l_ = __ffsll(m) - 1;
            m &= m - 1;
            const float ssc = __uint_as_float(
                __builtin_amdgcn_readlane(__float_as_uint(sc), l_));
            const int sid = c0 + 4 * l_ + ci;
            if ((ssc < tau[r]) || (ssc == tau[r] && sid < tix[r])) {
              const bool own = (lane == r);
              #pragma unroll
              for (int j = K_NN - 1; j >= 1; --j) {
                const bool  s1 = (best[j-1] > ssc) ||
                                 (best[j-1] == ssc && bix[j-1] > sid);
                const float nb = s1 ? best[j-1] : ssc;
                const int   ni = s1 ? bix[j-1]  : sid;
                const bool  wr = own && ((best[j] > ssc) ||
                                         (best[j] == ssc && bix[j] > sid));
                best[j] = wr ? nb : best[j];
                bix[j]  = wr ? ni : bix[j];
              }
              const bool w0 = own && ((best[0] > ssc) ||
                                      (best[0] == ssc && bix[0] > sid));
              bix[0]  = w0 ? sid : bix[0];
              best[0] = w0 ? ssc : best[0];
              tau[r] = __uint_as_float(
                  __builtin_amdgcn_readlane(__float_as_uint(best[K_NN-1]), r));
              tix[r] = __builtin_amdgcn_readlane(bix[K_NN-1], r);
            }
          }
        }
      }
    }

    __syncthreads();
    if (t + 1 < NTT) { WRITES(); __syncthreads(); }
  }

  // epilogue: lane r (0..3) of each wave owns row b0w+r
  if (lane < 4) {
    const int b = b0w + lane;
    const size_t base = (((size_t)b * A_ + a) * NCH + ch) * K_NN;
    #pragma unroll
    for (int j = 0; j < K_NN; ++j) {
      pscore[base + j] = best[j];
      pidx[base + j]   = bix[j];
    }
  }
#undef LOADS
#undef WRITES
#undef COMPUTE
}

// ---------------- K2: merge partial top-k, gather qvals, mean ----------------
__global__ __launch_bounds__(256) void merge_kernel(
    const float* __restrict__ pscore, const int* __restrict__ pidx,
    const float* __restrict__ qvals, float* __restrict__ qec)
{
  const int tt = blockIdx.x * 256 + threadIdx.x;  // tt = b*A + a
  if (tt >= B_ * A_) return;
  const int a = tt % A_;

  float best[K_NN]; int bix[K_NN];
  #pragma unroll
  for (int j = 0; j < K_NN; ++j) { best[j] = INFINITY; bix[j] = 0x7fffffff; }

  const float* ps = pscore + (size_t)tt * NCH * K_NN;
  const int*   pi = pidx   + (size_t)tt * NCH * K_NN;

  #pragma unroll
  for (int e = 0; e < NCH * K_NN; ++e) {
    float sc = ps[e]; int ci = pi[e];
    bool lt_last = (sc < best[K_NN-1]) || (sc == best[K_NN-1] && ci < bix[K_NN-1]);
    if (lt_last) {
      #pragma unroll
      for (int j = K_NN-1; j >= 1; --j) {
        bool  s1 = (best[j-1] > sc) || (best[j-1] == sc && bix[j-1] > ci);
        float nb = s1 ? best[j-1] : sc;
        int   ni = s1 ? bix[j-1]  : ci;
        bool  wr = (best[j] > sc) || (best[j] == sc && bix[j] > ci);
        if (wr) { best[j] = nb; bix[j] = ni; }
      }
      bool w0 = (best[0] > sc) || (best[0] == sc && bix[0] > ci);
      if (w0) { best[0] = sc; bix[0] = ci; }
    }
  }

  const float* qa = qvals + (size_t)a * C_;
  float s = 0.f;
  #pragma unroll
  for (int j = 0; j < K_NN; ++j) s += qa[bix[j]];
  qec[tt] = s / (float)K_NN;
}

// ---------------- K3: MLP + combine + argmax ----------------
__global__ __launch_bounds__(256) void mlp_kernel(
    const float* __restrict__ obs, const float* __restrict__ qec,
    const float* __restrict__ W1, const float* __restrict__ b1,
    const float* __restrict__ W2, const float* __restrict__ b2,
    const float* __restrict__ W3, const float* __restrict__ b3,
    float* __restrict__ out)
{
  const int wave = threadIdx.x >> 6;
  const int lane = threadIdx.x & 63;
  const int b = blockIdx.x * 4 + wave;

  float x = obs[(size_t)b * 64 + lane];

  float acc = b1[lane];
  #pragma unroll 8
  for (int d = 0; d < 64; ++d)
    acc = fmaf(__shfl(x, d, 64), W1[d * 64 + lane], acc);
  float h1 = fmaxf(acc, 0.f);

  float acc2 = b2[lane];
  #pragma unroll 8
  for (int d = 0; d < 64; ++d)
    acc2 = fmaf(__shfl(h1, d, 64), W2[d * 64 + lane], acc2);
  float h2 = fmaxf(acc2, 0.f);

  float p0 = h2 * W3[lane * 4 + 0];
  float p1 = h2 * W3[lane * 4 + 1];
  float p2 = h2 * W3[lane * 4 + 2];
  float p3 = h2 * W3[lane * 4 + 3];
  #pragma unroll
  for (int off = 32; off > 0; off >>= 1) {
    p0 += __shfl_xor(p0, off, 64);
    p1 += __shfl_xor(p1, off, 64);
    p2 += __shfl_xor(p2, off, 64);
    p3 += __shfl_xor(p3, off, 64);
  }

  if (lane == 0) {
    float q0 = 0.5f * (qec[b * 4 + 0] + (p0 + b3[0]));
    float q1 = 0.5f * (qec[b * 4 + 1] + (p1 + b3[1]));
    float q2 = 0.5f * (qec[b * 4 + 2] + (p2 + b3[2]));
    float q3 = 0.5f * (qec[b * 4 + 3] + (p3 + b3[3]));
    int am = 0; float m = q0;
    if (q1 > m) { m = q1; am = 1; }
    if (q2 > m) { m = q2; am = 2; }
    if (q3 > m) { m = q3; am = 3; }
    out[b] = (float)am;
    float* qrow = out + B_ + (size_t)b * 4;
    qrow[0] = q0; qrow[1] = q1; qrow[2] = q2; qrow[3] = q3;
  }
}

extern "C" void kernel_launch(void* const* d_in, const int* in_sizes, int n_in,
                              void* d_out, int out_size, void* d_ws, size_t ws_size,
                              hipStream_t stream) {
  const float* obs = (const float*)d_in[0];
  const float* ts  = (const float*)d_in[1];
  const float* qv  = (const float*)d_in[2];
  const float* W1  = (const float*)d_in[3];
  const float* b1  = (const float*)d_in[4];
  const float* W2  = (const float*)d_in[5];
  const float* b2  = (const float*)d_in[6];
  const float* W3  = (const float*)d_in[7];
  const float* b3  = (const float*)d_in[8];
  float* out = (float*)d_out;

  float* s2g    = (float*)d_ws;                                   // A*C
  float* qec    = s2g + (size_t)A_ * C_;                          // B*A
  float* pscore = qec + (size_t)B_ * A_;                          // B*A*NCH*K
  int*   pidx   = (int*)(pscore + (size_t)B_ * A_ * NCH * K_NN);  // same

  s2_kernel<<<dim3((A_ * C_ / 16 + 3) / 4), dim3(256), 0, stream>>>(ts, s2g);
  qec_kernel<<<dim3(1024), dim3(256), 0, stream>>>(obs, ts, s2g, pscore, pidx);
  merge_kernel<<<dim3((B_ * A_ + 255) / 256), dim3(256), 0, stream>>>(pscore, pidx, qv, qec);
  mlp_kernel<<<dim3(B_ / 4), dim3(256), 0, stream>>>(obs, qec, W1, b1, W2, b2, W3, b3, out);
}